// Round 25
// baseline (169.911 us; speedup 1.0000x reference)
//
#include <hip/hip_runtime.h>
#include <cfloat>
#include <cmath>

constexpr int B = 4;
constexpr int L = 4096;
constexpr int D = 512;
constexpr int NH = 8;
constexpr int DH = 64;
constexpr int KN = 16;
constexpr int M = B * L;          // 16384 rows
constexpr int N_IN = 3 * D;       // 1536
constexpr int NCELL = 512;        // 8x8x8 morton grid

typedef __attribute__((ext_vector_type(8))) short short8;   // 8 bf16 = 4 VGPR
typedef __attribute__((ext_vector_type(4))) float f32x4;    // MFMA acc
typedef unsigned short ushort;
typedef unsigned long long ull;

__device__ __forceinline__ ushort f2bf(float f) {   // RN-even bf16
  unsigned u = __float_as_uint(f);
  u = u + 0x7fffu + ((u >> 16) & 1u);
  return (ushort)(u >> 16);
}
__device__ __forceinline__ float bf2f(ushort h) {
  return __uint_as_float(((unsigned)h) << 16);
}
__device__ __forceinline__ float dot8(const uint4 qu, const uint4 ku, float a) {
  a = fmaf(bf2f((ushort)qu.x), bf2f((ushort)ku.x), a);
  a = fmaf(bf2f((ushort)(qu.x >> 16)), bf2f((ushort)(ku.x >> 16)), a);
  a = fmaf(bf2f((ushort)qu.y), bf2f((ushort)ku.y), a);
  a = fmaf(bf2f((ushort)(qu.y >> 16)), bf2f((ushort)(ku.y >> 16)), a);
  a = fmaf(bf2f((ushort)qu.z), bf2f((ushort)ku.z), a);
  a = fmaf(bf2f((ushort)(qu.z >> 16)), bf2f((ushort)(ku.z >> 16)), a);
  a = fmaf(bf2f((ushort)qu.w), bf2f((ushort)ku.w), a);
  a = fmaf(bf2f((ushort)(qu.w >> 16)), bf2f((ushort)(ku.w >> 16)), a);
  return a;
}
// weighted accumulate of one bf16x8 V-row into acc[8] (inline fn, not macro)
__device__ __forceinline__ void acc8(float wgt, const uint4 vv, float (&acc)[8]) {
  acc[0] = fmaf(wgt, bf2f((ushort)vv.x), acc[0]);
  acc[1] = fmaf(wgt, bf2f((ushort)(vv.x >> 16)), acc[1]);
  acc[2] = fmaf(wgt, bf2f((ushort)vv.y), acc[2]);
  acc[3] = fmaf(wgt, bf2f((ushort)(vv.y >> 16)), acc[3]);
  acc[4] = fmaf(wgt, bf2f((ushort)vv.z), acc[4]);
  acc[5] = fmaf(wgt, bf2f((ushort)(vv.z >> 16)), acc[5]);
  acc[6] = fmaf(wgt, bf2f((ushort)vv.w), acc[6]);
  acc[7] = fmaf(wgt, bf2f((ushort)(vv.w >> 16)), acc[7]);
}
__device__ __forceinline__ uint2 pack4hi(const float4 v) {
  uint2 o;
  o.x = (unsigned)f2bf(v.x) | ((unsigned)f2bf(v.y) << 16);
  o.y = (unsigned)f2bf(v.z) | ((unsigned)f2bf(v.w) << 16);
  return o;
}
// async global->LDS, 16B/lane, dest = wave-uniform base + lane*16
__device__ __forceinline__ void gload16(const void* g, void* l) {
  __builtin_amdgcn_global_load_lds(
      (const __attribute__((address_space(1))) void*)g,
      (__attribute__((address_space(3))) void*)l, 16, 0, 0);
}
__device__ __forceinline__ int morton3(int x, int y, int z) {  // 3 bits/dim
  int m = 0;
#pragma unroll
  for (int i = 0; i < 3; ++i)
    m |= (((x >> i) & 1) << (3 * i + 2)) | (((y >> i) & 1) << (3 * i + 1)) |
         (((z >> i) & 1) << (3 * i));
  return m;
}

constexpr int TP = 65;   // padded row stride (words), 65 % 32 == 1

// threshold search + phase B + rank + write for ONE query (R7 semantics).
__device__ __forceinline__ void topk_finish(
    const float* sxT, const float* syT, const float* szT, ull* lstw,
    const int lane, const float qx, const float qy, const float qz,
    const unsigned mbits, const int l, const int row,
    int* __restrict__ nbr, int* __restrict__ isin) {
  unsigned lo = 1, hi = 0x40400001u;
  while (lo < hi) {
    const unsigned mid = (lo + hi) >> 1;
    const int c = __popcll(__ballot(mbits < mid));
    if (c >= 16) hi = mid; else lo = mid + 1;
  }
  const unsigned P = lo + 16;

  int cnt = 0;
  ull am = __ballot(mbits < P);
  const ull below = (1ull << lane) - 1ull;
  while (am) {
    const int pl = (int)__builtin_ctzll(am);
    am &= am - 1;
    const int a = pl * TP + lane;
    const float dx = qx - sxT[a], dy = qy - syT[a], dz = qz - szT[a];
    const float d2 = fmaf(dx, dx, fmaf(dy, dy, dz * dz));
    const bool hit = __float_as_uint(d2) < P;
    const ull msk = __ballot(hit);
    if (hit) {
      const int slot = cnt + __popcll(msk & below);
      if (slot < 64) {
        const unsigned c = (unsigned)(lane * 64 + pl);
        lstw[slot] = ((ull)__float_as_uint(sqrtf(d2)) << 32) | c;
      }
    }
    cnt += __popcll(msk);
  }
  const int n = min(cnt, 64);

  const ull mine = (lane < n) ? lstw[lane] : ~0ull;
  int r = 0;
  for (int i = 0; i < n; ++i) r += (lstw[i] < mine) ? 1 : 0;

  const int idx = (int)(unsigned)(mine & 0xffffffffu);
  const bool wr = (lane < n) && (r < 16);
  if (wr) nbr[(size_t)row * KN + r] = idx;
  const ull hit2 = __ballot(wr && idx == l);
  if (lane == 0) isin[row] = hit2 ? 1 : 0;
}

// ---------------------------------------------------------------------------
// Kernel 0 (stage-0 light): sort (4 blks) | cvt_x (1024) | cvt_w (256).
// LDS 4 KB. Measured ~14 µs (R21).
// ---------------------------------------------------------------------------
constexpr int SORT_BLKS = B;             // 4
constexpr int CVTX_BLKS = 1024;
constexpr int CVTW_BLKS = 256;
constexpr int STAGE0_BLKS = SORT_BLKS + CVTX_BLKS + CVTW_BLKS;

__global__ __launch_bounds__(512) void stage0_kernel(
    const float* __restrict__ pos, const float* __restrict__ x,
    const float* __restrict__ in_w, const float* __restrict__ out_w,
    int* __restrict__ qorder, ushort* __restrict__ xb,
    ushort* __restrict__ iwh, ushort* __restrict__ owh,
    ushort* __restrict__ owl) {
  __shared__ int hist[NCELL];     // 2 KB
  __shared__ int scanbuf[NCELL];  // 2 KB

  const int bid = blockIdx.x;
  const int tid = threadIdx.x;

  if (bid < SORT_BLKS) {
    const int b = bid;
    const int t = tid;
    hist[t] = 0;
    __syncthreads();

    int cells[8], ranks[8];
    const float* p = pos + (size_t)b * L * 3;
#pragma unroll
    for (int q = 0; q < 8; ++q) {
      const int i = q * 512 + t;
      const int ix = min(7, max(0, (int)(p[3 * i + 0] * 8.f)));
      const int iy = min(7, max(0, (int)(p[3 * i + 1] * 8.f)));
      const int iz = min(7, max(0, (int)(p[3 * i + 2] * 8.f)));
      cells[q] = morton3(ix, iy, iz);
      ranks[q] = atomicAdd(&hist[cells[q]], 1);
    }
    __syncthreads();

    int accv = hist[t];
    const int orig = accv;
    scanbuf[t] = accv;
    __syncthreads();
    for (int s = 1; s < NCELL; s <<= 1) {
      const int o = (t >= s) ? scanbuf[t - s] : 0;
      __syncthreads();
      accv += o;
      scanbuf[t] = accv;
      __syncthreads();
    }
    hist[t] = accv - orig;   // exclusive offsets
    __syncthreads();

#pragma unroll
    for (int q = 0; q < 8; ++q) {
      const int i = q * 512 + t;
      qorder[b * L + hist[cells[q]] + ranks[q]] = i;
    }

  } else if (bid < SORT_BLKS + CVTX_BLKS) {
    const int vb = bid - SORT_BLKS;
    const int n8 = M * D / 8;
    for (int i = vb * 512 + tid; i < n8; i += CVTX_BLKS * 512) {
      const float4 v0 = reinterpret_cast<const float4*>(x)[i * 2];
      const float4 v1 = reinterpret_cast<const float4*>(x)[i * 2 + 1];
      uint4 o;
      const uint2 a = pack4hi(v0), b2 = pack4hi(v1);
      o.x = a.x; o.y = a.y; o.z = b2.x; o.w = b2.y;
      reinterpret_cast<uint4*>(xb)[i] = o;
    }

  } else {
    const int vb = bid - SORT_BLKS - CVTX_BLKS;
    const int ni8 = N_IN * D / 8;   // 98304
    const int no8 = D * D / 8;      // 32768
    for (int i = vb * 512 + tid; i < ni8 + no8; i += CVTW_BLKS * 512) {
      if (i < ni8) {
        const float4 v0 = reinterpret_cast<const float4*>(in_w)[i * 2];
        const float4 v1 = reinterpret_cast<const float4*>(in_w)[i * 2 + 1];
        uint4 o;
        const uint2 a = pack4hi(v0), b2 = pack4hi(v1);
        o.x = a.x; o.y = a.y; o.z = b2.x; o.w = b2.y;
        reinterpret_cast<uint4*>(iwh)[i] = o;
      } else {
        const int j = i - ni8;
        const float4 v0 = reinterpret_cast<const float4*>(out_w)[j * 2];
        const float4 v1 = reinterpret_cast<const float4*>(out_w)[j * 2 + 1];
        uint4 oh, ol;
        const uint2 a = pack4hi(v0), b2 = pack4hi(v1);
        oh.x = a.x; oh.y = a.y; oh.z = b2.x; oh.w = b2.y;
        const float4 r0 = make_float4(v0.x - bf2f(f2bf(v0.x)), v0.y - bf2f(f2bf(v0.y)),
                                      v0.z - bf2f(f2bf(v0.z)), v0.w - bf2f(f2bf(v0.w)));
        const float4 r1 = make_float4(v1.x - bf2f(f2bf(v1.x)), v1.y - bf2f(f2bf(v1.y)),
                                      v1.z - bf2f(f2bf(v1.z)), v1.w - bf2f(f2bf(v1.w)));
        const uint2 c = pack4hi(r0), d2 = pack4hi(r1);
        ol.x = c.x; ol.y = c.y; ol.z = d2.x; ol.w = d2.y;
        reinterpret_cast<uint4*>(owh)[j] = oh;
        reinterpret_cast<uint4*>(owl)[j] = ol;
      }
    }
  }
}

// ---------------------------------------------------------------------------
// Kernel 1 (R25: HORIZONTAL FUSION topk | gemm_in, both 256 threads).
// topk (1024 blocks, 4 waves x 4 queries = 16 q/block) issues pure VALU;
// gemm_in (1536 blocks) issues MFMA+memory — complementary pipes co-schedule
// (m114). topk blocks first in grid (long pole starts early). LDS union
// 51968 B (pos 49920 + lst 2048) -> 3 blocks/CU. Both branches' math
// verbatim -> outputs byte-identical.
// ---------------------------------------------------------------------------
constexpr int BM = 128, BN = 128;
constexpr int BK2 = 64;
constexpr int TOPK_BLKS = B * (L / 16);  // 1024
constexpr int GEMM_BLKS = (M / BM) * (N_IN / BN);  // 1536
constexpr int K1_BLKS = TOPK_BLKS + GEMM_BLKS;

__global__ __launch_bounds__(256) void topk_gemm_kernel(
    const float* __restrict__ pos, const ushort* __restrict__ A,
    const ushort* __restrict__ W, const float* __restrict__ bias,
    int* __restrict__ nbr, int* __restrict__ isin,
    ushort* __restrict__ qb, ushort* __restrict__ kb,
    ushort* __restrict__ vb) {
  // union: topk = sxT/syT/szT (49920B) + lst (4 waves * 64 * 8 = 2048B)
  //        gemm = Ah (16384B) + Bh (16384B)
  __shared__ ull smem_u64[51968 / 8];

  const int bid = blockIdx.x;
  const int tid = threadIdx.x;

  if (bid < TOPK_BLKS) {
    // ---- top-16 NN, 4 waves x 4 queries (R24 math, 256 threads) ----
    float* sxT = (float*)smem_u64;
    float* syT = sxT + 64 * TP;
    float* szT = syT + 64 * TP;
    ull* lst = (ull*)(szT + 64 * TP);

    const int wave = tid >> 6;
    const int lane = tid & 63;
    const int b = bid >> 8;                 // 256 blocks per batch
    const int l0 = (bid & 255) * 16 + wave * 4;

    const float* p = pos + (size_t)b * L * 3;
    for (int i = tid; i < L; i += 256) {
      const int a = (i & 63) * TP + (i >> 6);
      sxT[a] = p[3 * i + 0];
      syT[a] = p[3 * i + 1];
      szT[a] = p[3 * i + 2];
    }
    __syncthreads();

    float qx[4], qy[4], qz[4], mn[4];
#pragma unroll
    for (int q = 0; q < 4; ++q) {
      const int lq = l0 + q;
      const int qa = (lq & 63) * TP + (lq >> 6);
      qx[q] = sxT[qa];
      qy[q] = syT[qa];
      qz[q] = szT[qa];
      mn[q] = FLT_MAX;
    }

    const int base = lane * TP;
    for (int j = 0; j < 64; ++j) {
      const int a = base + j;
      const float cx = sxT[a], cy = syT[a], cz = szT[a];
#pragma unroll
      for (int q = 0; q < 4; ++q) {
        const float dx = qx[q] - cx, dy = qy[q] - cy, dz = qz[q] - cz;
        mn[q] = fminf(mn[q], fmaf(dx, dx, fmaf(dy, dy, dz * dz)));
      }
    }

    ull* lstw = lst + wave * 64;
#pragma unroll
    for (int q = 0; q < 4; ++q)
      topk_finish(sxT, syT, szT, lstw, lane, qx[q], qy[q], qz[q],
                  __float_as_uint(mn[q]), l0 + q, b * L + l0 + q, nbr, isin);

  } else {
    // ---- in_proj GEMM (BK=64, swizzled staging; R16 math verbatim) ----
    ushort* Ah = (ushort*)smem_u64;
    ushort* Bh = Ah + BM * BK2;

    const int gbid = bid - TOPK_BLKS;
    const int m0 = (gbid & 127) * BM;        // 128 m-tiles
    const int n0 = (gbid >> 7) * BN;         // 12 n-tiles

    const int wv = tid >> 6;
    const int lane = tid & 63;
    const int srow0 = wv * 8 + (lane >> 3);
    const int gchunk = (lane & 7) ^ (lane >> 3);   // inverse swizzle on source
    const ushort* Asrc = A + (size_t)(m0 + srow0) * D + gchunk * 8;
    const ushort* Wsrc = W + (size_t)(n0 + srow0) * D + gchunk * 8;
    ushort* AhB0 = Ah + (wv * 8) * BK2;
    ushort* AhB1 = Ah + (wv * 8 + 32) * BK2;
    ushort* AhB2 = Ah + (wv * 8 + 64) * BK2;
    ushort* AhB3 = Ah + (wv * 8 + 96) * BK2;
    ushort* BhB0 = Bh + (wv * 8) * BK2;
    ushort* BhB1 = Bh + (wv * 8 + 32) * BK2;
    ushort* BhB2 = Bh + (wv * 8 + 64) * BK2;
    ushort* BhB3 = Bh + (wv * 8 + 96) * BK2;

    const int wr0 = (wv >> 1) * 64;
    const int wc0 = (wv & 1) * 64;
    const int fr_row = lane & 15;
    const int cbase = lane >> 4;
    const int rx = lane & 7;

    f32x4 acc[4][4];
#pragma unroll
    for (int i = 0; i < 4; ++i)
#pragma unroll
      for (int j = 0; j < 4; ++j) acc[i][j] = {0.f, 0.f, 0.f, 0.f};

    for (int k0 = 0; k0 < D; k0 += BK2) {
      __syncthreads();
      gload16(Asrc + k0, AhB0);
      gload16(Asrc + (size_t)32 * D + k0, AhB1);
      gload16(Asrc + (size_t)64 * D + k0, AhB2);
      gload16(Asrc + (size_t)96 * D + k0, AhB3);
      gload16(Wsrc + k0, BhB0);
      gload16(Wsrc + (size_t)32 * D + k0, BhB1);
      gload16(Wsrc + (size_t)64 * D + k0, BhB2);
      gload16(Wsrc + (size_t)96 * D + k0, BhB3);
      __syncthreads();

#pragma unroll
      for (int kk = 0; kk < 2; ++kk) {
        const int slot = (kk * 4 + cbase) ^ rx;
        short8 ah[4];
#pragma unroll
        for (int fr = 0; fr < 4; ++fr)
          ah[fr] = *reinterpret_cast<const short8*>(
              &Ah[(wr0 + fr * 16 + fr_row) * BK2 + slot * 8]);
#pragma unroll
        for (int fc = 0; fc < 4; ++fc) {
          const short8 bh = *reinterpret_cast<const short8*>(
              &Bh[(wc0 + fc * 16 + fr_row) * BK2 + slot * 8]);
#pragma unroll
          for (int fr = 0; fr < 4; ++fr)
            acc[fr][fc] = __builtin_amdgcn_mfma_f32_16x16x32_bf16(ah[fr], bh, acc[fr][fc], 0, 0, 0);
        }
      }
    }

    const int region = n0 >> 9;             // 0=q, 1=k, 2=v
    ushort* outb = region == 0 ? qb : (region == 1 ? kb : vb);
    const float scl = region == 0 ? 0.125f : 1.0f;
    const int nloc0 = (n0 & 511) + wc0;
#pragma unroll
    for (int fr = 0; fr < 4; ++fr) {
#pragma unroll
      for (int r = 0; r < 4; ++r) {
        const int grow = m0 + wr0 + fr * 16 + (lane >> 4) * 4 + r;
#pragma unroll
        for (int fc = 0; fc < 4; ++fc) {
          const int cc = fc * 16 + (lane & 15);
          const float v = (acc[fr][fc][r] + bias[n0 + wc0 + cc]) * scl;
          outb[(size_t)grow * D + nloc0 + cc] = f2bf(v);
        }
      }
    }
  }
}

// ---------------------------------------------------------------------------
// Kernel 2b: out_proj, BK=64 + swizzled staging, W hi/lo (bit-exact).
// ---------------------------------------------------------------------------
__global__ __launch_bounds__(256) void gemm_out(const ushort* __restrict__ A,
                                                const ushort* __restrict__ Wh,
                                                const ushort* __restrict__ Wl,
                                                const float* __restrict__ bias,
                                                float* __restrict__ C,
                                                const float* __restrict__ X,
                                                const int* __restrict__ isin) {
  __shared__ ushort Ah[BM * BK2];   // 16 KB
  __shared__ ushort Bh[BN * BK2];   // 16 KB
  __shared__ ushort Bl[BN * BK2];   // 16 KB

  const int tid = threadIdx.x;
  const int m0 = blockIdx.x * BM;
  const int n0 = blockIdx.y * BN;

  const int wv = tid >> 6;
  const int lane = tid & 63;
  const int srow0 = wv * 8 + (lane >> 3);
  const int gchunk = (lane & 7) ^ (lane >> 3);
  const ushort* Asrc = A + (size_t)(m0 + srow0) * D + gchunk * 8;
  const ushort* Hsrc = Wh + (size_t)(n0 + srow0) * D + gchunk * 8;
  const ushort* Lsrc = Wl + (size_t)(n0 + srow0) * D + gchunk * 8;
  ushort* AhB0 = Ah + (wv * 8) * BK2;
  ushort* AhB1 = Ah + (wv * 8 + 32) * BK2;
  ushort* AhB2 = Ah + (wv * 8 + 64) * BK2;
  ushort* AhB3 = Ah + (wv * 8 + 96) * BK2;
  ushort* BhB0 = Bh + (wv * 8) * BK2;
  ushort* BhB1 = Bh + (wv * 8 + 32) * BK2;
  ushort* BhB2 = Bh + (wv * 8 + 64) * BK2;
  ushort* BhB3 = Bh + (wv * 8 + 96) * BK2;
  ushort* BlB0 = Bl + (wv * 8) * BK2;
  ushort* BlB1 = Bl + (wv * 8 + 32) * BK2;
  ushort* BlB2 = Bl + (wv * 8 + 64) * BK2;
  ushort* BlB3 = Bl + (wv * 8 + 96) * BK2;

  const int wr0 = (wv >> 1) * 64;
  const int wc0 = (wv & 1) * 64;
  const int fr_row = lane & 15;
  const int cbase = lane >> 4;
  const int rx = lane & 7;

  f32x4 acc[4][4];
#pragma unroll
  for (int i = 0; i < 4; ++i)
#pragma unroll
    for (int j = 0; j < 4; ++j) acc[i][j] = {0.f, 0.f, 0.f, 0.f};

  for (int k0 = 0; k0 < D; k0 += BK2) {
    __syncthreads();
    gload16(Asrc + k0, AhB0);
    gload16(Asrc + (size_t)32 * D + k0, AhB1);
    gload16(Asrc + (size_t)64 * D + k0, AhB2);
    gload16(Asrc + (size_t)96 * D + k0, AhB3);
    gload16(Hsrc + k0, BhB0);
    gload16(Hsrc + (size_t)32 * D + k0, BhB1);
    gload16(Hsrc + (size_t)64 * D + k0, BhB2);
    gload16(Hsrc + (size_t)96 * D + k0, BhB3);
    gload16(Lsrc + k0, BlB0);
    gload16(Lsrc + (size_t)32 * D + k0, BlB1);
    gload16(Lsrc + (size_t)64 * D + k0, BlB2);
    gload16(Lsrc + (size_t)96 * D + k0, BlB3);
    __syncthreads();

#pragma unroll
    for (int kk = 0; kk < 2; ++kk) {
      const int slot = (kk * 4 + cbase) ^ rx;
      short8 ah[4];
#pragma unroll
      for (int fr = 0; fr < 4; ++fr)
        ah[fr] = *reinterpret_cast<const short8*>(
            &Ah[(wr0 + fr * 16 + fr_row) * BK2 + slot * 8]);
#pragma unroll
      for (int fc = 0; fc < 4; ++fc) {
        const short8 bh = *reinterpret_cast<const short8*>(
            &Bh[(wc0 + fc * 16 + fr_row) * BK2 + slot * 8]);
        const short8 bl = *reinterpret_cast<const short8*>(
            &Bl[(wc0 + fc * 16 + fr_row) * BK2 + slot * 8]);
#pragma unroll
        for (int fr = 0; fr < 4; ++fr) {
          acc[fr][fc] = __builtin_amdgcn_mfma_f32_16x16x32_bf16(ah[fr], bh, acc[fr][fc], 0, 0, 0);
          acc[fr][fc] = __builtin_amdgcn_mfma_f32_16x16x32_bf16(ah[fr], bl, acc[fr][fc], 0, 0, 0);
        }
      }
    }
  }

#pragma unroll
  for (int fr = 0; fr < 4; ++fr) {
#pragma unroll
    for (int r = 0; r < 4; ++r) {
      const int grow = m0 + wr0 + fr * 16 + (lane >> 4) * 4 + r;
      const int ok = isin[grow];
#pragma unroll
      for (int fc = 0; fc < 4; ++fc) {
        const int gcol = n0 + wc0 + fc * 16 + (lane & 15);
        float v = acc[fr][fc][r] + bias[gcol];
        if (!ok) v = X[(size_t)grow * D + gcol];
        C[(size_t)grow * D + gcol] = v;
      }
    }
  }
}

// ---------------------------------------------------------------------------
// Kernel 3: fused gathered attention (R13 version — best measured, 51 µs).
// ---------------------------------------------------------------------------
__global__ __launch_bounds__(256) void attn_kernel(const ushort* __restrict__ qb,
                                                   const ushort* __restrict__ kb,
                                                   const ushort* __restrict__ vb,
                                                   const int* __restrict__ nbr,
                                                   const int* __restrict__ qorder,
                                                   ushort* __restrict__ ctx) {
  const int wave = threadIdx.x >> 6;
  const int lane = threadIdx.x & 63;
  const int xcd = blockIdx.x & 7;
  const int chunk = blockIdx.x >> 3;           // 0..511
  const int b = xcd >> 1;
  const int slot = ((xcd & 1) * 512 + chunk) * 4 + wave;   // 0..4095 sorted
  const int l = qorder[b * L + slot];
  const int bl = b * L + l;
  const int bbase = b * L;
  const int* nb = nbr + (size_t)bl * KN;

  const int h = lane >> 3;
  const int n0 = lane & 7;
  const int glane = h * 8;

  const ushort* qp = qb + (size_t)bl * D + h * DH;
  uint4 qv[8];
#pragma unroll
  for (int i = 0; i < 8; ++i)
    qv[i] = *reinterpret_cast<const uint4*>(qp + i * 8);

  const int j0 = nb[n0];
  const int j1 = nb[n0 + 8];
  float a0 = 0.f, a1 = 0.f;
  {
    const ushort* kr0 = kb + (size_t)(bbase + j0) * D + h * DH;
    const ushort* kr1 = kb + (size_t)(bbase + j1) * D + h * DH;
#pragma unroll
    for (int i = 0; i < 8; ++i) {
      a0 = dot8(qv[i], *reinterpret_cast<const uint4*>(kr0 + i * 8), a0);
      a1 = dot8(qv[i], *reinterpret_cast<const uint4*>(kr1 + i * 8), a1);
    }
  }

  // softmax over the 8-lane head group (2 scores per lane)
  float mx = fmaxf(a0, a1);
  mx = fmaxf(mx, __shfl_xor(mx, 1));
  mx = fmaxf(mx, __shfl_xor(mx, 2));
  mx = fmaxf(mx, __shfl_xor(mx, 4));
  const float e0 = expf(a0 - mx), e1 = expf(a1 - mx);
  float sm = e0 + e1;
  sm += __shfl_xor(sm, 1);
  sm += __shfl_xor(sm, 2);
  sm += __shfl_xor(sm, 4);
  const float inv = 1.0f / sm;
  const float w0 = e0 * inv, w1 = e1 * inv;

  // hoisted per-n broadcasts (full unroll -> static indices -> registers)
  float ww[KN];
  int jj[KN];
#pragma unroll
  for (int n = 0; n < KN; ++n) {
    const int src = glane + (n & 7);
    ww[n] = __shfl((n < 8) ? w0 : w1, src);
    jj[n] = __shfl((n < 8) ? j0 : j1, src);
  }

  const int d0 = n0 * 8;
  const ushort* vbase = vb + (size_t)bbase * D + h * DH + d0;
  float acc[8];
#pragma unroll
  for (int i = 0; i < 8; ++i) acc[i] = 0.f;

#pragma unroll
  for (int g = 0; g < KN; g += 4) {
    const uint4 va0 = *reinterpret_cast<const uint4*>(vbase + (size_t)jj[g] * D);
    const uint4 va1 = *reinterpret_cast<const uint4*>(vbase + (size_t)jj[g + 1] * D);
    const uint4 va2 = *reinterpret_cast<const uint4*>(vbase + (size_t)jj[g + 2] * D);
    const uint4 va3 = *reinterpret_cast<const uint4*>(vbase + (size_t)jj[g + 3] * D);
    acc8(ww[g], va0, acc);
    acc8(ww[g + 1], va1, acc);
    acc8(ww[g + 2], va2, acc);
    acc8(ww[g + 3], va3, acc);
  }

  uint4 o;
  o.x = (unsigned)f2bf(acc[0]) | ((unsigned)f2bf(acc[1]) << 16);
  o.y = (unsigned)f2bf(acc[2]) | ((unsigned)f2bf(acc[3]) << 16);
  o.z = (unsigned)f2bf(acc[4]) | ((unsigned)f2bf(acc[5]) << 16);
  o.w = (unsigned)f2bf(acc[6]) | ((unsigned)f2bf(acc[7]) << 16);
  *reinterpret_cast<uint4*>(ctx + (size_t)bl * D + h * DH + d0) = o;
}

// ---------------------------------------------------------------------------
extern "C" void kernel_launch(void* const* d_in, const int* in_sizes, int n_in,
                              void* d_out, int out_size, void* d_ws, size_t ws_size,
                              hipStream_t stream) {
  const float* x     = (const float*)d_in[0];
  const float* pos   = (const float*)d_in[1];
  const float* in_w  = (const float*)d_in[2];
  const float* in_b  = (const float*)d_in[3];
  const float* out_w = (const float*)d_in[4];
  const float* out_b = (const float*)d_in[5];
  float* out = (float*)d_out;

  const size_t nbr_bytes  = (size_t)M * KN * sizeof(int);       // 1 MB
  const size_t isin_bytes = (size_t)M * sizeof(int);            // 64 KB
  const size_t half_bytes = (size_t)M * D * sizeof(ushort);     // 16.8 MB
  const size_t iwh_bytes  = (size_t)N_IN * D * sizeof(ushort);  // 1.5 MB
  const size_t ow_bytes   = (size_t)D * D * sizeof(ushort);     // 0.5 MB
  const size_t sort_bytes = (size_t)M * sizeof(int);            // 64 KB
  const size_t need = nbr_bytes + isin_bytes + 5 * half_bytes +
                      iwh_bytes + 2 * ow_bytes + sort_bytes + 16384;
  if (ws_size < need) return;

  char* w = (char*)d_ws;
  int*    nbr    = (int*)w;    w += (nbr_bytes + 255) & ~(size_t)255;
  int*    isin   = (int*)w;    w += (isin_bytes + 255) & ~(size_t)255;
  ushort* xb     = (ushort*)w; w += (half_bytes + 255) & ~(size_t)255;
  ushort* qb     = (ushort*)w; w += (half_bytes + 255) & ~(size_t)255;
  ushort* kb     = (ushort*)w; w += (half_bytes + 255) & ~(size_t)255;
  ushort* vb     = (ushort*)w; w += (half_bytes + 255) & ~(size_t)255;
  ushort* ctxb   = (ushort*)w; w += (half_bytes + 255) & ~(size_t)255;
  ushort* iwh    = (ushort*)w; w += (iwh_bytes + 255) & ~(size_t)255;
  ushort* owh    = (ushort*)w; w += (ow_bytes + 255) & ~(size_t)255;
  ushort* owl    = (ushort*)w; w += (ow_bytes + 255) & ~(size_t)255;
  int*    qorder = (int*)w;

  // 0) stage-0 light: sort | cvt_x | cvt_w (~14 µs)
  stage0_kernel<<<STAGE0_BLKS, 512, 0, stream>>>(
      pos, x, in_w, out_w, qorder, xb, iwh, owh, owl);

  // 1) HORIZONTAL FUSION: topk (VALU pipe) | in_proj GEMM (MFMA pipe)
  topk_gemm_kernel<<<K1_BLKS, 256, 0, stream>>>(
      pos, xb, iwh, in_b, nbr, isin, qb, kb, vb);

  // 2) fused gathered attention (R13) -> bf16 ctx
  attn_kernel<<<M / 4, 256, 0, stream>>>(qb, kb, vb, nbr, qorder, ctxb);

  // 3) out_proj (BK=64, swizzled staging, W hi/lo) + isin select
  gemm_out<<<dim3(M / BM, D / BN), 256, 0, stream>>>(ctxb, owh, owl, out_b, out, x, isin);
}

// Round 26
// 145.463 us; speedup vs baseline: 1.1681x; 1.1681x over previous
//
#include <hip/hip_runtime.h>
#include <cfloat>
#include <cmath>

constexpr int B = 4;
constexpr int L = 4096;
constexpr int D = 512;
constexpr int NH = 8;
constexpr int DH = 64;
constexpr int KN = 16;
constexpr int M = B * L;          // 16384 rows
constexpr int N_IN = 3 * D;       // 1536
constexpr int NCELL = 512;        // 8x8x8 morton grid

typedef __attribute__((ext_vector_type(8))) short short8;   // 8 bf16 = 4 VGPR
typedef __attribute__((ext_vector_type(4))) float f32x4;    // MFMA acc
typedef unsigned short ushort;
typedef unsigned long long ull;

__device__ __forceinline__ ushort f2bf(float f) {   // RN-even bf16
  unsigned u = __float_as_uint(f);
  u = u + 0x7fffu + ((u >> 16) & 1u);
  return (ushort)(u >> 16);
}
__device__ __forceinline__ float bf2f(ushort h) {
  return __uint_as_float(((unsigned)h) << 16);
}
__device__ __forceinline__ float dot8(const uint4 qu, const uint4 ku, float a) {
  a = fmaf(bf2f((ushort)qu.x), bf2f((ushort)ku.x), a);
  a = fmaf(bf2f((ushort)(qu.x >> 16)), bf2f((ushort)(ku.x >> 16)), a);
  a = fmaf(bf2f((ushort)qu.y), bf2f((ushort)ku.y), a);
  a = fmaf(bf2f((ushort)(qu.y >> 16)), bf2f((ushort)(ku.y >> 16)), a);
  a = fmaf(bf2f((ushort)qu.z), bf2f((ushort)ku.z), a);
  a = fmaf(bf2f((ushort)(qu.z >> 16)), bf2f((ushort)(ku.z >> 16)), a);
  a = fmaf(bf2f((ushort)qu.w), bf2f((ushort)ku.w), a);
  a = fmaf(bf2f((ushort)(qu.w >> 16)), bf2f((ushort)(ku.w >> 16)), a);
  return a;
}
// weighted accumulate of one bf16x8 V-row into acc[8] (inline fn, not macro)
__device__ __forceinline__ void acc8(float wgt, const uint4 vv, float (&acc)[8]) {
  acc[0] = fmaf(wgt, bf2f((ushort)vv.x), acc[0]);
  acc[1] = fmaf(wgt, bf2f((ushort)(vv.x >> 16)), acc[1]);
  acc[2] = fmaf(wgt, bf2f((ushort)vv.y), acc[2]);
  acc[3] = fmaf(wgt, bf2f((ushort)(vv.y >> 16)), acc[3]);
  acc[4] = fmaf(wgt, bf2f((ushort)vv.z), acc[4]);
  acc[5] = fmaf(wgt, bf2f((ushort)(vv.z >> 16)), acc[5]);
  acc[6] = fmaf(wgt, bf2f((ushort)vv.w), acc[6]);
  acc[7] = fmaf(wgt, bf2f((ushort)(vv.w >> 16)), acc[7]);
}
__device__ __forceinline__ uint2 pack4hi(const float4 v) {
  uint2 o;
  o.x = (unsigned)f2bf(v.x) | ((unsigned)f2bf(v.y) << 16);
  o.y = (unsigned)f2bf(v.z) | ((unsigned)f2bf(v.w) << 16);
  return o;
}
// async global->LDS, 16B/lane, dest = wave-uniform base + lane*16
__device__ __forceinline__ void gload16(const void* g, void* l) {
  __builtin_amdgcn_global_load_lds(
      (const __attribute__((address_space(1))) void*)g,
      (__attribute__((address_space(3))) void*)l, 16, 0, 0);
}
__device__ __forceinline__ int morton3(int x, int y, int z) {  // 3 bits/dim
  int m = 0;
#pragma unroll
  for (int i = 0; i < 3; ++i)
    m |= (((x >> i) & 1) << (3 * i + 2)) | (((y >> i) & 1) << (3 * i + 1)) |
         (((z >> i) & 1) << (3 * i));
  return m;
}

constexpr int TP = 65;   // padded row stride (words), 65 % 32 == 1

// threshold search + phase B + rank + write for ONE query (R7 semantics).
__device__ __forceinline__ void topk_finish(
    const float* sxT, const float* syT, const float* szT, ull* lstw,
    const int lane, const float qx, const float qy, const float qz,
    const unsigned mbits, const int l, const int row,
    int* __restrict__ nbr, int* __restrict__ isin) {
  unsigned lo = 1, hi = 0x40400001u;
  while (lo < hi) {
    const unsigned mid = (lo + hi) >> 1;
    const int c = __popcll(__ballot(mbits < mid));
    if (c >= 16) hi = mid; else lo = mid + 1;
  }
  const unsigned P = lo + 16;

  int cnt = 0;
  ull am = __ballot(mbits < P);
  const ull below = (1ull << lane) - 1ull;
  while (am) {
    const int pl = (int)__builtin_ctzll(am);
    am &= am - 1;
    const int a = pl * TP + lane;
    const float dx = qx - sxT[a], dy = qy - syT[a], dz = qz - szT[a];
    const float d2 = fmaf(dx, dx, fmaf(dy, dy, dz * dz));
    const bool hit = __float_as_uint(d2) < P;
    const ull msk = __ballot(hit);
    if (hit) {
      const int slot = cnt + __popcll(msk & below);
      if (slot < 64) {
        const unsigned c = (unsigned)(lane * 64 + pl);
        lstw[slot] = ((ull)__float_as_uint(sqrtf(d2)) << 32) | c;
      }
    }
    cnt += __popcll(msk);
  }
  const int n = min(cnt, 64);

  const ull mine = (lane < n) ? lstw[lane] : ~0ull;
  int r = 0;
  for (int i = 0; i < n; ++i) r += (lstw[i] < mine) ? 1 : 0;

  const int idx = (int)(unsigned)(mine & 0xffffffffu);
  const bool wr = (lane < n) && (r < 16);
  if (wr) nbr[(size_t)row * KN + r] = idx;
  const ull hit2 = __ballot(wr && idx == l);
  if (lane == 0) isin[row] = hit2 ? 1 : 0;
}

// ---------------------------------------------------------------------------
// Kernel 0 (FUSED stage-0, R24): topk 4-queries/wave (512 blks) | sort (4)
// | cvt_x (1024) | cvt_w (256). LDS union 54016 B -> 3 blocks/CU.
// topk phase A reads each candidate ONCE for 4 queries; finish per query.
// ---------------------------------------------------------------------------
constexpr int TOPK_BLKS = B * (L / 32);  // 512 (32 queries/block)
constexpr int SORT_BLKS = B;             // 4
constexpr int CVTX_BLKS = 1024;
constexpr int CVTW_BLKS = 256;
constexpr int STAGE0_BLKS = TOPK_BLKS + SORT_BLKS + CVTX_BLKS + CVTW_BLKS;

__global__ __launch_bounds__(512) void stage0_kernel(
    const float* __restrict__ pos, const float* __restrict__ x,
    const float* __restrict__ in_w, const float* __restrict__ out_w,
    int* __restrict__ nbr, int* __restrict__ isin, int* __restrict__ qorder,
    ushort* __restrict__ xb, ushort* __restrict__ iwh,
    ushort* __restrict__ owh, ushort* __restrict__ owl) {
  // union: topk = sxT/syT/szT (3*16640B) + lst (4096B) = 54016 B
  //        sort = hist(2048B) scanbuf(2048B)
  __shared__ ull smem_u64[54016 / 8];

  const int bid = blockIdx.x;
  const int tid = threadIdx.x;

  if (bid < TOPK_BLKS) {
    // ---- top-16 NN, 4 queries per wave ----
    float* sxT = (float*)smem_u64;
    float* syT = sxT + 64 * TP;
    float* szT = syT + 64 * TP;
    ull* lst = (ull*)(szT + 64 * TP);

    const int wave = tid >> 6;
    const int lane = tid & 63;
    const int b = bid >> 7;                 // 128 blocks per batch
    const int l0 = (bid & 127) * 32 + wave * 4;

    const float* p = pos + (size_t)b * L * 3;
    for (int i = tid; i < L; i += 512) {
      const int a = (i & 63) * TP + (i >> 6);
      sxT[a] = p[3 * i + 0];
      syT[a] = p[3 * i + 1];
      szT[a] = p[3 * i + 2];
    }
    __syncthreads();

    float qx[4], qy[4], qz[4], mn[4];
#pragma unroll
    for (int q = 0; q < 4; ++q) {
      const int lq = l0 + q;
      const int qa = (lq & 63) * TP + (lq >> 6);
      qx[q] = sxT[qa];
      qy[q] = syT[qa];
      qz[q] = szT[qa];
      mn[q] = FLT_MAX;
    }

    // phase A: read each candidate once, track min d2 for all 4 queries
    const int base = lane * TP;
    for (int j = 0; j < 64; ++j) {
      const int a = base + j;
      const float cx = sxT[a], cy = syT[a], cz = szT[a];
#pragma unroll
      for (int q = 0; q < 4; ++q) {
        const float dx = qx[q] - cx, dy = qy[q] - cy, dz = qz[q] - cz;
        mn[q] = fminf(mn[q], fmaf(dx, dx, fmaf(dy, dy, dz * dz)));
      }
    }

    ull* lstw = lst + wave * 64;
#pragma unroll
    for (int q = 0; q < 4; ++q)
      topk_finish(sxT, syT, szT, lstw, lane, qx[q], qy[q], qz[q],
                  __float_as_uint(mn[q]), l0 + q, b * L + l0 + q, nbr, isin);

  } else if (bid < TOPK_BLKS + SORT_BLKS) {
    // ---- morton counting sort (one block per batch) ----
    int* hist = (int*)smem_u64;
    int* scanbuf = hist + NCELL;
    const int b = bid - TOPK_BLKS;
    const int t = tid;
    hist[t] = 0;
    __syncthreads();

    int cells[8], ranks[8];
    const float* p = pos + (size_t)b * L * 3;
#pragma unroll
    for (int q = 0; q < 8; ++q) {
      const int i = q * 512 + t;
      const int ix = min(7, max(0, (int)(p[3 * i + 0] * 8.f)));
      const int iy = min(7, max(0, (int)(p[3 * i + 1] * 8.f)));
      const int iz = min(7, max(0, (int)(p[3 * i + 2] * 8.f)));
      cells[q] = morton3(ix, iy, iz);
      ranks[q] = atomicAdd(&hist[cells[q]], 1);
    }
    __syncthreads();

    int accv = hist[t];
    const int orig = accv;
    scanbuf[t] = accv;
    __syncthreads();
    for (int s = 1; s < NCELL; s <<= 1) {
      const int o = (t >= s) ? scanbuf[t - s] : 0;
      __syncthreads();
      accv += o;
      scanbuf[t] = accv;
      __syncthreads();
    }
    hist[t] = accv - orig;   // exclusive offsets
    __syncthreads();

#pragma unroll
    for (int q = 0; q < 8; ++q) {
      const int i = q * 512 + t;
      qorder[b * L + hist[cells[q]] + ranks[q]] = i;
    }

  } else if (bid < TOPK_BLKS + SORT_BLKS + CVTX_BLKS) {
    // ---- x (fp32) -> xb (bf16) ----
    const int vb = bid - TOPK_BLKS - SORT_BLKS;
    const int n8 = M * D / 8;
    for (int i = vb * 512 + tid; i < n8; i += CVTX_BLKS * 512) {
      const float4 v0 = reinterpret_cast<const float4*>(x)[i * 2];
      const float4 v1 = reinterpret_cast<const float4*>(x)[i * 2 + 1];
      uint4 o;
      const uint2 a = pack4hi(v0), b2 = pack4hi(v1);
      o.x = a.x; o.y = a.y; o.z = b2.x; o.w = b2.y;
      reinterpret_cast<uint4*>(xb)[i] = o;
    }

  } else {
    // ---- weights: in_w -> iwh (hi); out_w -> owh + owl (hi/lo) ----
    const int vb = bid - TOPK_BLKS - SORT_BLKS - CVTX_BLKS;
    const int ni8 = N_IN * D / 8;   // 98304
    const int no8 = D * D / 8;      // 32768
    for (int i = vb * 512 + tid; i < ni8 + no8; i += CVTW_BLKS * 512) {
      if (i < ni8) {
        const float4 v0 = reinterpret_cast<const float4*>(in_w)[i * 2];
        const float4 v1 = reinterpret_cast<const float4*>(in_w)[i * 2 + 1];
        uint4 o;
        const uint2 a = pack4hi(v0), b2 = pack4hi(v1);
        o.x = a.x; o.y = a.y; o.z = b2.x; o.w = b2.y;
        reinterpret_cast<uint4*>(iwh)[i] = o;
      } else {
        const int j = i - ni8;
        const float4 v0 = reinterpret_cast<const float4*>(out_w)[j * 2];
        const float4 v1 = reinterpret_cast<const float4*>(out_w)[j * 2 + 1];
        uint4 oh, ol;
        const uint2 a = pack4hi(v0), b2 = pack4hi(v1);
        oh.x = a.x; oh.y = a.y; oh.z = b2.x; oh.w = b2.y;
        const float4 r0 = make_float4(v0.x - bf2f(f2bf(v0.x)), v0.y - bf2f(f2bf(v0.y)),
                                      v0.z - bf2f(f2bf(v0.z)), v0.w - bf2f(f2bf(v0.w)));
        const float4 r1 = make_float4(v1.x - bf2f(f2bf(v1.x)), v1.y - bf2f(f2bf(v1.y)),
                                      v1.z - bf2f(f2bf(v1.z)), v1.w - bf2f(f2bf(v1.w)));
        const uint2 c = pack4hi(r0), d2 = pack4hi(r1);
        ol.x = c.x; ol.y = c.y; ol.z = d2.x; ol.w = d2.y;
        reinterpret_cast<uint4*>(owh)[j] = oh;
        reinterpret_cast<uint4*>(owl)[j] = ol;
      }
    }
  }
}

// ---------------------------------------------------------------------------
// GEMM tiles: 128x128, 4 waves (2x2 of 64x64), 16x16x32 bf16 MFMA.
// BK=64 with XOR-swizzled staging (rule #21): LDS linear; global SOURCE
// chunk pre-swizzled g=(lane&7)^(lane>>3); READ slot = chunk ^ (row&7).
// C/D layout col=lane&15, row=(lane>>4)*4+r  [m89-verified]
// ---------------------------------------------------------------------------
constexpr int BM = 128, BN = 128;
constexpr int BK2 = 64;

__global__ __launch_bounds__(256) void gemm_in(const ushort* __restrict__ A,
                                               const ushort* __restrict__ W,
                                               const float* __restrict__ bias,
                                               ushort* __restrict__ qb,
                                               ushort* __restrict__ kb,
                                               ushort* __restrict__ vb) {
  __shared__ ushort Ah[BM * BK2];   // 16 KB, linear
  __shared__ ushort Bh[BN * BK2];   // 16 KB, linear

  const int tid = threadIdx.x;
  const int m0 = blockIdx.x * BM;
  const int n0 = blockIdx.y * BN;

  const int wv = tid >> 6;
  const int lane = tid & 63;
  const int srow0 = wv * 8 + (lane >> 3);
  const int gchunk = (lane & 7) ^ (lane >> 3);     // inverse swizzle on source
  const ushort* Asrc = A + (size_t)(m0 + srow0) * D + gchunk * 8;
  const ushort* Wsrc = W + (size_t)(n0 + srow0) * D + gchunk * 8;
  ushort* AhB0 = Ah + (wv * 8) * BK2;
  ushort* AhB1 = Ah + (wv * 8 + 32) * BK2;
  ushort* AhB2 = Ah + (wv * 8 + 64) * BK2;
  ushort* AhB3 = Ah + (wv * 8 + 96) * BK2;
  ushort* BhB0 = Bh + (wv * 8) * BK2;
  ushort* BhB1 = Bh + (wv * 8 + 32) * BK2;
  ushort* BhB2 = Bh + (wv * 8 + 64) * BK2;
  ushort* BhB3 = Bh + (wv * 8 + 96) * BK2;

  const int wr0 = (wv >> 1) * 64;
  const int wc0 = (wv & 1) * 64;
  const int fr_row = lane & 15;
  const int cbase = lane >> 4;
  const int rx = lane & 7;

  f32x4 acc[4][4];
#pragma unroll
  for (int i = 0; i < 4; ++i)
#pragma unroll
    for (int j = 0; j < 4; ++j) acc[i][j] = {0.f, 0.f, 0.f, 0.f};

  for (int k0 = 0; k0 < D; k0 += BK2) {
    __syncthreads();
    gload16(Asrc + k0, AhB0);
    gload16(Asrc + (size_t)32 * D + k0, AhB1);
    gload16(Asrc + (size_t)64 * D + k0, AhB2);
    gload16(Asrc + (size_t)96 * D + k0, AhB3);
    gload16(Wsrc + k0, BhB0);
    gload16(Wsrc + (size_t)32 * D + k0, BhB1);
    gload16(Wsrc + (size_t)64 * D + k0, BhB2);
    gload16(Wsrc + (size_t)96 * D + k0, BhB3);
    __syncthreads();

#pragma unroll
    for (int kk = 0; kk < 2; ++kk) {
      const int slot = (kk * 4 + cbase) ^ rx;
      short8 ah[4];
#pragma unroll
      for (int fr = 0; fr < 4; ++fr)
        ah[fr] = *reinterpret_cast<const short8*>(
            &Ah[(wr0 + fr * 16 + fr_row) * BK2 + slot * 8]);
#pragma unroll
      for (int fc = 0; fc < 4; ++fc) {
        const short8 bh = *reinterpret_cast<const short8*>(
            &Bh[(wc0 + fc * 16 + fr_row) * BK2 + slot * 8]);
#pragma unroll
        for (int fr = 0; fr < 4; ++fr)
          acc[fr][fc] = __builtin_amdgcn_mfma_f32_16x16x32_bf16(ah[fr], bh, acc[fr][fc], 0, 0, 0);
      }
    }
  }

  const int region = n0 >> 9;             // 0=q, 1=k, 2=v
  ushort* outb = region == 0 ? qb : (region == 1 ? kb : vb);
  const float scl = region == 0 ? 0.125f : 1.0f;
  const int nloc0 = (n0 & 511) + wc0;
#pragma unroll
  for (int fr = 0; fr < 4; ++fr) {
#pragma unroll
    for (int r = 0; r < 4; ++r) {
      const int grow = m0 + wr0 + fr * 16 + (lane >> 4) * 4 + r;
#pragma unroll
      for (int fc = 0; fc < 4; ++fc) {
        const int cc = fc * 16 + (lane & 15);
        const float v = (acc[fr][fc][r] + bias[n0 + wc0 + cc]) * scl;
        outb[(size_t)grow * D + nloc0 + cc] = f2bf(v);
      }
    }
  }
}

__global__ __launch_bounds__(256) void gemm_out(const ushort* __restrict__ A,
                                                const ushort* __restrict__ Wh,
                                                const ushort* __restrict__ Wl,
                                                const float* __restrict__ bias,
                                                float* __restrict__ C,
                                                const float* __restrict__ X,
                                                const int* __restrict__ isin) {
  __shared__ ushort Ah[BM * BK2];   // 16 KB
  __shared__ ushort Bh[BN * BK2];   // 16 KB
  __shared__ ushort Bl[BN * BK2];   // 16 KB

  const int tid = threadIdx.x;
  const int m0 = blockIdx.x * BM;
  const int n0 = blockIdx.y * BN;

  const int wv = tid >> 6;
  const int lane = tid & 63;
  const int srow0 = wv * 8 + (lane >> 3);
  const int gchunk = (lane & 7) ^ (lane >> 3);
  const ushort* Asrc = A + (size_t)(m0 + srow0) * D + gchunk * 8;
  const ushort* Hsrc = Wh + (size_t)(n0 + srow0) * D + gchunk * 8;
  const ushort* Lsrc = Wl + (size_t)(n0 + srow0) * D + gchunk * 8;
  ushort* AhB0 = Ah + (wv * 8) * BK2;
  ushort* AhB1 = Ah + (wv * 8 + 32) * BK2;
  ushort* AhB2 = Ah + (wv * 8 + 64) * BK2;
  ushort* AhB3 = Ah + (wv * 8 + 96) * BK2;
  ushort* BhB0 = Bh + (wv * 8) * BK2;
  ushort* BhB1 = Bh + (wv * 8 + 32) * BK2;
  ushort* BhB2 = Bh + (wv * 8 + 64) * BK2;
  ushort* BhB3 = Bh + (wv * 8 + 96) * BK2;
  ushort* BlB0 = Bl + (wv * 8) * BK2;
  ushort* BlB1 = Bl + (wv * 8 + 32) * BK2;
  ushort* BlB2 = Bl + (wv * 8 + 64) * BK2;
  ushort* BlB3 = Bl + (wv * 8 + 96) * BK2;

  const int wr0 = (wv >> 1) * 64;
  const int wc0 = (wv & 1) * 64;
  const int fr_row = lane & 15;
  const int cbase = lane >> 4;
  const int rx = lane & 7;

  f32x4 acc[4][4];
#pragma unroll
  for (int i = 0; i < 4; ++i)
#pragma unroll
    for (int j = 0; j < 4; ++j) acc[i][j] = {0.f, 0.f, 0.f, 0.f};

  for (int k0 = 0; k0 < D; k0 += BK2) {
    __syncthreads();
    gload16(Asrc + k0, AhB0);
    gload16(Asrc + (size_t)32 * D + k0, AhB1);
    gload16(Asrc + (size_t)64 * D + k0, AhB2);
    gload16(Asrc + (size_t)96 * D + k0, AhB3);
    gload16(Hsrc + k0, BhB0);
    gload16(Hsrc + (size_t)32 * D + k0, BhB1);
    gload16(Hsrc + (size_t)64 * D + k0, BhB2);
    gload16(Hsrc + (size_t)96 * D + k0, BhB3);
    gload16(Lsrc + k0, BlB0);
    gload16(Lsrc + (size_t)32 * D + k0, BlB1);
    gload16(Lsrc + (size_t)64 * D + k0, BlB2);
    gload16(Lsrc + (size_t)96 * D + k0, BlB3);
    __syncthreads();

#pragma unroll
    for (int kk = 0; kk < 2; ++kk) {
      const int slot = (kk * 4 + cbase) ^ rx;
      short8 ah[4];
#pragma unroll
      for (int fr = 0; fr < 4; ++fr)
        ah[fr] = *reinterpret_cast<const short8*>(
            &Ah[(wr0 + fr * 16 + fr_row) * BK2 + slot * 8]);
#pragma unroll
      for (int fc = 0; fc < 4; ++fc) {
        const short8 bh = *reinterpret_cast<const short8*>(
            &Bh[(wc0 + fc * 16 + fr_row) * BK2 + slot * 8]);
        const short8 bl = *reinterpret_cast<const short8*>(
            &Bl[(wc0 + fc * 16 + fr_row) * BK2 + slot * 8]);
#pragma unroll
        for (int fr = 0; fr < 4; ++fr) {
          acc[fr][fc] = __builtin_amdgcn_mfma_f32_16x16x32_bf16(ah[fr], bh, acc[fr][fc], 0, 0, 0);
          acc[fr][fc] = __builtin_amdgcn_mfma_f32_16x16x32_bf16(ah[fr], bl, acc[fr][fc], 0, 0, 0);
        }
      }
    }
  }

#pragma unroll
  for (int fr = 0; fr < 4; ++fr) {
#pragma unroll
    for (int r = 0; r < 4; ++r) {
      const int grow = m0 + wr0 + fr * 16 + (lane >> 4) * 4 + r;
      const int ok = isin[grow];
#pragma unroll
      for (int fc = 0; fc < 4; ++fc) {
        const int gcol = n0 + wc0 + fc * 16 + (lane & 15);
        float v = acc[fr][fc][r] + bias[gcol];
        if (!ok) v = X[(size_t)grow * D + gcol];
        C[(size_t)grow * D + gcol] = v;
      }
    }
  }
}

// ---------------------------------------------------------------------------
// Kernel 3: fused gathered attention (R13 version — best measured, 51 µs).
// Sorted order + XCD affinity, shuffle softmax, hoisted (w,j), 4-batched PV.
// ---------------------------------------------------------------------------
__global__ __launch_bounds__(256) void attn_kernel(const ushort* __restrict__ qb,
                                                   const ushort* __restrict__ kb,
                                                   const ushort* __restrict__ vb,
                                                   const int* __restrict__ nbr,
                                                   const int* __restrict__ qorder,
                                                   ushort* __restrict__ ctx) {
  const int wave = threadIdx.x >> 6;
  const int lane = threadIdx.x & 63;
  const int xcd = blockIdx.x & 7;
  const int chunk = blockIdx.x >> 3;           // 0..511
  const int b = xcd >> 1;
  const int slot = ((xcd & 1) * 512 + chunk) * 4 + wave;   // 0..4095 sorted
  const int l = qorder[b * L + slot];
  const int bl = b * L + l;
  const int bbase = b * L;
  const int* nb = nbr + (size_t)bl * KN;

  const int h = lane >> 3;
  const int n0 = lane & 7;
  const int glane = h * 8;

  const ushort* qp = qb + (size_t)bl * D + h * DH;
  uint4 qv[8];
#pragma unroll
  for (int i = 0; i < 8; ++i)
    qv[i] = *reinterpret_cast<const uint4*>(qp + i * 8);

  const int j0 = nb[n0];
  const int j1 = nb[n0 + 8];
  float a0 = 0.f, a1 = 0.f;
  {
    const ushort* kr0 = kb + (size_t)(bbase + j0) * D + h * DH;
    const ushort* kr1 = kb + (size_t)(bbase + j1) * D + h * DH;
#pragma unroll
    for (int i = 0; i < 8; ++i) {
      a0 = dot8(qv[i], *reinterpret_cast<const uint4*>(kr0 + i * 8), a0);
      a1 = dot8(qv[i], *reinterpret_cast<const uint4*>(kr1 + i * 8), a1);
    }
  }

  // softmax over the 8-lane head group (2 scores per lane)
  float mx = fmaxf(a0, a1);
  mx = fmaxf(mx, __shfl_xor(mx, 1));
  mx = fmaxf(mx, __shfl_xor(mx, 2));
  mx = fmaxf(mx, __shfl_xor(mx, 4));
  const float e0 = expf(a0 - mx), e1 = expf(a1 - mx);
  float sm = e0 + e1;
  sm += __shfl_xor(sm, 1);
  sm += __shfl_xor(sm, 2);
  sm += __shfl_xor(sm, 4);
  const float inv = 1.0f / sm;
  const float w0 = e0 * inv, w1 = e1 * inv;

  // hoisted per-n broadcasts (full unroll -> static indices -> registers)
  float ww[KN];
  int jj[KN];
#pragma unroll
  for (int n = 0; n < KN; ++n) {
    const int src = glane + (n & 7);
    ww[n] = __shfl((n < 8) ? w0 : w1, src);
    jj[n] = __shfl((n < 8) ? j0 : j1, src);
  }

  const int d0 = n0 * 8;
  const ushort* vbase = vb + (size_t)bbase * D + h * DH + d0;
  float acc[8];
#pragma unroll
  for (int i = 0; i < 8; ++i) acc[i] = 0.f;

#pragma unroll
  for (int g = 0; g < KN; g += 4) {
    const uint4 va0 = *reinterpret_cast<const uint4*>(vbase + (size_t)jj[g] * D);
    const uint4 va1 = *reinterpret_cast<const uint4*>(vbase + (size_t)jj[g + 1] * D);
    const uint4 va2 = *reinterpret_cast<const uint4*>(vbase + (size_t)jj[g + 2] * D);
    const uint4 va3 = *reinterpret_cast<const uint4*>(vbase + (size_t)jj[g + 3] * D);
    acc8(ww[g], va0, acc);
    acc8(ww[g + 1], va1, acc);
    acc8(ww[g + 2], va2, acc);
    acc8(ww[g + 3], va3, acc);
  }

  uint4 o;
  o.x = (unsigned)f2bf(acc[0]) | ((unsigned)f2bf(acc[1]) << 16);
  o.y = (unsigned)f2bf(acc[2]) | ((unsigned)f2bf(acc[3]) << 16);
  o.z = (unsigned)f2bf(acc[4]) | ((unsigned)f2bf(acc[5]) << 16);
  o.w = (unsigned)f2bf(acc[6]) | ((unsigned)f2bf(acc[7]) << 16);
  *reinterpret_cast<uint4*>(ctx + (size_t)bl * D + h * DH + d0) = o;
}

// ---------------------------------------------------------------------------
extern "C" void kernel_launch(void* const* d_in, const int* in_sizes, int n_in,
                              void* d_out, int out_size, void* d_ws, size_t ws_size,
                              hipStream_t stream) {
  const float* x     = (const float*)d_in[0];
  const float* pos   = (const float*)d_in[1];
  const float* in_w  = (const float*)d_in[2];
  const float* in_b  = (const float*)d_in[3];
  const float* out_w = (const float*)d_in[4];
  const float* out_b = (const float*)d_in[5];
  float* out = (float*)d_out;

  const size_t nbr_bytes  = (size_t)M * KN * sizeof(int);       // 1 MB
  const size_t isin_bytes = (size_t)M * sizeof(int);            // 64 KB
  const size_t half_bytes = (size_t)M * D * sizeof(ushort);     // 16.8 MB
  const size_t iwh_bytes  = (size_t)N_IN * D * sizeof(ushort);  // 1.5 MB
  const size_t ow_bytes   = (size_t)D * D * sizeof(ushort);     // 0.5 MB
  const size_t sort_bytes = (size_t)M * sizeof(int);            // 64 KB
  const size_t need = nbr_bytes + isin_bytes + 5 * half_bytes +
                      iwh_bytes + 2 * ow_bytes + sort_bytes + 16384;
  if (ws_size < need) return;

  char* w = (char*)d_ws;
  int*    nbr    = (int*)w;    w += (nbr_bytes + 255) & ~(size_t)255;
  int*    isin   = (int*)w;    w += (isin_bytes + 255) & ~(size_t)255;
  ushort* xb     = (ushort*)w; w += (half_bytes + 255) & ~(size_t)255;
  ushort* qb     = (ushort*)w; w += (half_bytes + 255) & ~(size_t)255;
  ushort* kb     = (ushort*)w; w += (half_bytes + 255) & ~(size_t)255;
  ushort* vb     = (ushort*)w; w += (half_bytes + 255) & ~(size_t)255;
  ushort* ctxb   = (ushort*)w; w += (half_bytes + 255) & ~(size_t)255;
  ushort* iwh    = (ushort*)w; w += (iwh_bytes + 255) & ~(size_t)255;
  ushort* owh    = (ushort*)w; w += (ow_bytes + 255) & ~(size_t)255;
  ushort* owl    = (ushort*)w; w += (ow_bytes + 255) & ~(size_t)255;
  int*    qorder = (int*)w;

  // 0) fused stage-0 (4 queries/wave topk): topk | sort | cvt_x | cvt_w
  stage0_kernel<<<STAGE0_BLKS, 512, 0, stream>>>(
      pos, x, in_w, out_w, nbr, isin, qorder, xb, iwh, owh, owl);

  // 1) in_proj (BK=64, swizzled staging) -> bf16 Q(scaled)/K/V
  gemm_in<<<dim3(M / BM, N_IN / BN), 256, 0, stream>>>(xb, iwh, in_b, qb, kb, vb);

  // 2) fused gathered attention (R13) -> bf16 ctx
  attn_kernel<<<M / 4, 256, 0, stream>>>(qb, kb, vb, nbr, qorder, ctxb);

  // 3) out_proj (BK=64, swizzled staging, W hi/lo) + isin select
  gemm_out<<<dim3(M / BM, D / BN), 256, 0, stream>>>(ctxb, owh, owl, out_b, out, x, isin);
}